// Round 9
// baseline (10432.224 us; speedup 1.0000x reference)
//
#include <hip/hip_runtime.h>
#include <math.h>

typedef short short8 __attribute__((ext_vector_type(8)));
typedef float f32x4 __attribute__((ext_vector_type(4)));
typedef unsigned long long u64;
typedef u64 u64x2 __attribute__((ext_vector_type(2)));

#define DT 0.042f
#define LSEQ 512
#define NI 96
#define NH 1024

static __device__ __forceinline__ unsigned short f2bf(float f) {
  unsigned int u = __builtin_bit_cast(unsigned int, f);
  return (unsigned short)((u + 0x7fffu + ((u >> 16) & 1u)) >> 16);
}
static __device__ __forceinline__ float bf2f(unsigned short h) {
  unsigned int u = ((unsigned int)h) << 16;
  return __builtin_bit_cast(float, u);
}
static __device__ __forceinline__ float fast_tanhf(float a) {
  float ax = __builtin_fabsf(a);
  float e = __expf(2.0f * ax);  // overflow -> inf -> t = 1, no NaN
  float t = 1.0f - 2.0f / (e + 1.0f);
  return a < 0.0f ? -t : t;
}

// F=true: sc0 ops (XCD-local L2) for verified co-XCD groups — data AND flags.
// F=false: relaxed agent atomics via IC (proven rounds 2/3/5/8).
template <bool F>
static __device__ __forceinline__ void ld16_issue(u64x2* dst, const u64* p) {
  if constexpr (F) {
    asm volatile("global_load_dwordx4 %0, %1, off sc0" : "=v"(*dst) : "v"(p) : "memory");
  } else {
    u64 a = __hip_atomic_load(p, __ATOMIC_RELAXED, __HIP_MEMORY_SCOPE_AGENT);
    u64 b = __hip_atomic_load(p + 1, __ATOMIC_RELAXED, __HIP_MEMORY_SCOPE_AGENT);
    *dst = (u64x2){a, b};
  }
}
template <bool F>
static __device__ __forceinline__ void ld_fence() {  // A-frags resident (rule #18)
  if constexpr (F) {
    asm volatile("s_waitcnt vmcnt(0)" ::: "memory");
    __builtin_amdgcn_sched_barrier(0);
  }
}
template <bool F>
static __device__ __forceinline__ unsigned int ldflag(const unsigned int* p) {
  if constexpr (F) {
    unsigned int r;
    asm volatile("global_load_dword %0, %1, off sc0\n\ts_waitcnt vmcnt(0)"
                 : "=v"(r) : "v"(p) : "memory");
    __builtin_amdgcn_sched_barrier(0);
    return r;
  } else {
    return __hip_atomic_load(p, __ATOMIC_RELAXED, __HIP_MEMORY_SCOPE_AGENT);
  }
}
template <bool F>
static __device__ __forceinline__ void stpub(unsigned int* p, unsigned int v) {
  if constexpr (F)
    asm volatile("global_store_dword %0, %1, off sc0" ::"v"(p), "v"(v) : "memory");
  else
    __hip_atomic_store(p, v, __ATOMIC_RELAXED, __HIP_MEMORY_SCOPE_AGENT);
}
template <bool F>
static __device__ __forceinline__ void stflag(unsigned int* p, unsigned int v) {
  if constexpr (F)
    asm volatile("global_store_dword %0, %1, off sc0" ::"v"(p), "v"(v) : "memory");
  else
    __hip_atomic_store(p, v, __ATOMIC_RELAXED, __HIP_MEMORY_SCOPE_AGENT);
}
static __device__ __forceinline__ void drain_vm() {  // wave-local: my stores committed
  asm volatile("s_waitcnt vmcnt(0)" ::: "memory");
  __builtin_amdgcn_sched_barrier(0);
}
template <bool B> struct BoolC { static constexpr bool value = B; };

// 256 blocks x 512 threads. Group g (16 batch rows) x col-block jb (32 cols); 8 waves
// k-split 1024 (wave w: k-tiles w*4..+3). PER-WAVE flags (2 per block: one per
// publishing wave) -> publisher drains only its own stores and posts immediately;
// consumers watch 8 flags (4 suppliers x 2 halves). ONE barrier/step (LDS part[]
// double-buffered by s&1); waves 2-7 run ahead into step s+1 while waves 0/1 finish
// step s. Triple-buffered hy_ex: union of the 8 waves' watch sets = all 32 producers
// -> buffer (s-3)%3 fully read before overwrite (r5 invariant, re-derived).
// Mapping (g, jb, fast) from block-0-built table (actual XCD placement, r8-proven);
// fast groups use sc0 (XCD L2) for data+flags; leftovers use agent/IC everywhere.
__global__ __launch_bounds__(512, 2) void ron_kernel(
    const float* __restrict__ x, const float* __restrict__ x2h,
    const float* __restrict__ h2h, const float* __restrict__ bias,
    const float* __restrict__ gam_, const float* __restrict__ eps_,
    float* __restrict__ out, unsigned int* __restrict__ flags,
    unsigned int* __restrict__ hy_ex) {
  const int tid = threadIdx.x;
  const int w = tid >> 6;  // 0..7
  const int l = tid & 63;
  const int lc = l & 15;
  const int kg = l >> 4;

  __shared__ f32x4 part[2][8][2][64];  // 32KB, double-buffered by s&1
  __shared__ int info_sh;

  unsigned int* base = flags + 8192;  // byte 32768
  unsigned int* xcdtab = base;        // [0..255]
  unsigned int* ctr = base + 256;
  unsigned int* abortw = base + 257;
  unsigned int* enttab = base + 272;  // [0..255]

  // ---- publish my XCD (every block) ----
  if (tid == 0) {
    unsigned int myxcd = __builtin_amdgcn_s_getreg(63508) & 15u;  // hwreg(XCC_ID=20,0,32)
    __hip_atomic_store(xcdtab + blockIdx.x, 0x100u | myxcd, __ATOMIC_RELAXED,
                       __HIP_MEMORY_SCOPE_AGENT);
    __hip_atomic_fetch_add(ctr, 1u, __ATOMIC_RELAXED, __HIP_MEMORY_SCOPE_AGENT);
  }

  // ---- block 0: build the (g, jb, mode) table — single source of truth (r8-proven) ----
  if (blockIdx.x == 0 && tid == 0) {
    int gu = 0;
    while (__hip_atomic_load(ctr, __ATOMIC_RELAXED, __HIP_MEMORY_SCOPE_AGENT) < 256u) {
      if (++gu > (1 << 17)) break;
      __builtin_amdgcn_s_sleep(8);
    }
    bool ok = (gu <= (1 << 17));
    unsigned char xs[256];
    if (ok) {
      for (int i = 0; i < 256; ++i) {
        unsigned int v = __hip_atomic_load(xcdtab + i, __ATOMIC_RELAXED, __HIP_MEMORY_SCOPE_AGENT);
        int g2 = 0;
        while (v == 0 && ++g2 <= 8192) {
          __builtin_amdgcn_s_sleep(2);
          v = __hip_atomic_load(xcdtab + i, __ATOMIC_RELAXED, __HIP_MEMORY_SCOPE_AGENT);
        }
        if (v == 0) { ok = false; break; }
        xs[i] = (unsigned char)(v & 15u);
      }
    }
    unsigned int ent[256];
    if (ok) {
      int gidx = 0, nl = 0;
      unsigned char left[256], tmp[256];
      for (unsigned int xc = 0; xc < 16u && gidx < 8; ++xc) {
        int cnt = 0;
        for (int i = 0; i < 256; ++i)
          if (xs[i] == (unsigned char)xc) tmp[cnt++] = (unsigned char)i;
        int p = 0;
        while (cnt - p >= 32 && gidx < 8) {  // exact-32 co-XCD set -> fast
          for (int k2 = 0; k2 < 32; ++k2)
            ent[tmp[p + k2]] = 1u | ((unsigned)gidx << 1) | ((unsigned)k2 << 4) | (1u << 9);
          ++gidx; p += 32;
        }
        for (; p < cnt; ++p) left[nl++] = tmp[p];
      }
      int li = 0;
      while (gidx < 8) {  // mixed leftovers -> slow (agent/IC, proven)
        for (int k2 = 0; k2 < 32 && li < nl; ++k2, ++li)
          ent[left[li]] = 1u | ((unsigned)gidx << 1) | ((unsigned)k2 << 4);
        ++gidx;
      }
    } else {
      for (int i = 0; i < 256; ++i)
        ent[i] = 1u | ((unsigned)(i & 7) << 1) | ((unsigned)(i >> 3) << 4);
    }
    for (int i = 0; i < 256; ++i)
      __hip_atomic_store(enttab + i, ent[i], __ATOMIC_RELAXED, __HIP_MEMORY_SCOPE_AGENT);
  }

  // ---- every block: fetch my entry ----
  if (tid == 0) {
    unsigned int e = 0;
    int gu = 0;
    for (;;) {
      e = __hip_atomic_load(enttab + blockIdx.x, __ATOMIC_RELAXED, __HIP_MEMORY_SCOPE_AGENT);
      if (e || ++gu > (1 << 17)) break;
      __builtin_amdgcn_s_sleep(16);
    }
    if (!e) e = 1u | ((unsigned)(blockIdx.x & 7) << 1) | ((unsigned)(blockIdx.x >> 3) << 4);
    info_sh = (int)e;
  }
  __syncthreads();
  const unsigned int ent = (unsigned int)info_sh;
  const int g = (ent >> 1) & 7;
  const int jb = (ent >> 4) & 31;
  const bool fastm = ((ent >> 9) & 1) != 0;

  // ---- one-time: h2h k-slice (wave's 4 k-tiles) x 2 col-tiles, hi/lo bf16 ----
  short8 wfh[4][2], wfl[4][2];
#pragma unroll
  for (int j = 0; j < 4; ++j) {
    const int krow = (w * 4 + j) * 32 + kg * 8;
#pragma unroll
    for (int t = 0; t < 2; ++t) {
      const int c = jb * 32 + t * 16 + lc;
#pragma unroll
      for (int jj = 0; jj < 8; ++jj) {
        float v = h2h[(size_t)(krow + jj) * NH + c];
        unsigned short hb = f2bf(v);
        wfh[j][t][jj] = (short)hb;
        wfl[j][t][jj] = (short)f2bf(v - bf2f(hb));
      }
    }
  }
  const int myc = jb * 32 + w * 16 + lc;  // owned col (waves 0,1 only)
  short8 xwh[3], xwl[3];
  float bias_c = 0.f, gam = 0.f, ep = 0.f;
  if (w < 2) {
#pragma unroll
    for (int kt = 0; kt < 3; ++kt)
#pragma unroll
      for (int jj = 0; jj < 8; ++jj) {
        float v = x2h[(size_t)(kt * 32 + kg * 8 + jj) * NH + myc];
        unsigned short hb = f2bf(v);
        xwh[kt][jj] = (short)hb;
        xwl[kt][jj] = (short)f2bf(v - bf2f(hb));
      }
    bias_c = bias[myc];
    gam = gam_[myc];
    ep = eps_[myc];
  }

  float hy[4] = {0.f, 0.f, 0.f, 0.f};
  float hz[4] = {0.f, 0.f, 0.f, 0.f};
  const float* xlane = x + (size_t)(g * 16 + lc) * LSEQ * NI + kg * 8;
  const int aoff = lc * 8 + kg * 2;  // u64 units within a 128-u64 chunk
  // per-wave flags: 64 per group, 64B-spaced
  unsigned int* myflag = flags + (size_t)(g * 64 + jb * 2 + w) * 16;  // (w<2 only)
  unsigned int* watch =
      flags + (size_t)(g * 64 + (w * 4 + ((l >> 1) & 3)) * 2 + (l & 1)) * 16;
  const int ktc = myc >> 5, kgc = (myc >> 3) & 3, sh = myc & 7;

  // ---- prefetch x for s=0 ----
  f32x4 xr[6];
  if (w < 2) {
#pragma unroll
    for (int kt = 0; kt < 3; ++kt) {
      xr[2 * kt] = *(const f32x4*)(xlane + kt * 32);
      xr[2 * kt + 1] = *(const f32x4*)(xlane + kt * 32 + 4);
    }
  }

  auto run = [&](auto fc) {
    constexpr bool F = decltype(fc)::value;
    bool noSync = false;  // watchdog: trip -> never wait again (fast, visible failure)
    for (int s = 0; s < LSEQ; ++s) {
      const int wb = s % 3;            // write buffer
      const int rb = wb ? wb - 1 : 2;  // read buffer = (s-1)%3

      // ---- pack x(s) frags from prefetched regs ----
      short8 axh[3], axl[3];
      if (w < 2) {
#pragma unroll
        for (int kt = 0; kt < 3; ++kt) {
#pragma unroll
          for (int jj = 0; jj < 4; ++jj) {
            unsigned short hb = f2bf(xr[2 * kt][jj]);
            axh[kt][jj] = (short)hb;
            axl[kt][jj] = (short)f2bf(xr[2 * kt][jj] - bf2f(hb));
            unsigned short hb2 = f2bf(xr[2 * kt + 1][jj]);
            axh[kt][jj + 4] = (short)hb2;
            axl[kt][jj + 4] = (short)f2bf(xr[2 * kt + 1][jj] - bf2f(hb2));
          }
        }
      }

      f32x4 a0a = {0.f, 0.f, 0.f, 0.f}, a0b = {0.f, 0.f, 0.f, 0.f};
      f32x4 a1a = {0.f, 0.f, 0.f, 0.f}, a1b = {0.f, 0.f, 0.f, 0.f};
      f32x4 accx = {0.f, 0.f, 0.f, 0.f};
      u64x2 hq[4], lq[4];

      if (s) {
        // ---- wait: 4 suppliers x 2 publishing waves (8 flags via l&7) ----
        if (!noSync) {
          int guard = 0;
          for (;;) {
            unsigned int v = ldflag<F>(watch);
            if (!__any((int)v < s)) break;
            if ((++guard & 255) == 0) {
              if (__hip_atomic_load(abortw, __ATOMIC_RELAXED, __HIP_MEMORY_SCOPE_AGENT) != 0u ||
                  guard > (1 << 16)) {
                __hip_atomic_store(abortw, 1u, __ATOMIC_RELAXED, __HIP_MEMORY_SCOPE_AGENT);
                noSync = true;
                break;
              }
            }
            __builtin_amdgcn_s_sleep(1);
          }
        }
        asm volatile("" ::: "memory");  // keep A-loads below the spin

        // ---- issue A-fragment loads (wave's k-quarter: 8 x 16B) ----
        const u64* srcg = (const u64*)hy_ex + (size_t)(rb * 8 + g) * 8192;
#pragma unroll
        for (int j = 0; j < 4; ++j) {
          const int idx = (w * 4 + j) * 128 + aoff;
          ld16_issue<F>(&hq[j], srcg + idx);
          ld16_issue<F>(&lq[j], srcg + 4096 + idx);
        }
      }

      // ---- x-projection MFMAs (waves 0,1): overlap the A-load round trip ----
      if (w < 2) {
#pragma unroll
        for (int kt = 0; kt < 3; ++kt) {
          accx = __builtin_amdgcn_mfma_f32_16x16x32_bf16(axh[kt], xwh[kt], accx, 0, 0, 0);
          accx = __builtin_amdgcn_mfma_f32_16x16x32_bf16(axl[kt], xwh[kt], accx, 0, 0, 0);
          accx = __builtin_amdgcn_mfma_f32_16x16x32_bf16(axh[kt], xwl[kt], accx, 0, 0, 0);
        }
      }

      if (s) {
        ld_fence<F>();
#pragma unroll
        for (int j = 0; j < 4; ++j) {
          short8 fh = __builtin_bit_cast(short8, hq[j]);
          short8 fl = __builtin_bit_cast(short8, lq[j]);
          if (j & 1) {
            a0b = __builtin_amdgcn_mfma_f32_16x16x32_bf16(fh, wfh[j][0], a0b, 0, 0, 0);
            a1b = __builtin_amdgcn_mfma_f32_16x16x32_bf16(fh, wfh[j][1], a1b, 0, 0, 0);
            a0b = __builtin_amdgcn_mfma_f32_16x16x32_bf16(fl, wfh[j][0], a0b, 0, 0, 0);
            a1b = __builtin_amdgcn_mfma_f32_16x16x32_bf16(fl, wfh[j][1], a1b, 0, 0, 0);
            a0b = __builtin_amdgcn_mfma_f32_16x16x32_bf16(fh, wfl[j][0], a0b, 0, 0, 0);
            a1b = __builtin_amdgcn_mfma_f32_16x16x32_bf16(fh, wfl[j][1], a1b, 0, 0, 0);
          } else {
            a0a = __builtin_amdgcn_mfma_f32_16x16x32_bf16(fh, wfh[j][0], a0a, 0, 0, 0);
            a1a = __builtin_amdgcn_mfma_f32_16x16x32_bf16(fh, wfh[j][1], a1a, 0, 0, 0);
            a0a = __builtin_amdgcn_mfma_f32_16x16x32_bf16(fl, wfh[j][0], a0a, 0, 0, 0);
            a1a = __builtin_amdgcn_mfma_f32_16x16x32_bf16(fl, wfh[j][1], a1a, 0, 0, 0);
            a0a = __builtin_amdgcn_mfma_f32_16x16x32_bf16(fh, wfl[j][0], a0a, 0, 0, 0);
            a1a = __builtin_amdgcn_mfma_f32_16x16x32_bf16(fh, wfl[j][1], a1a, 0, 0, 0);
          }
        }
      }

      // ---- cross-wave k-reduction via LDS (double-buffered; ONE barrier/step) ----
      part[s & 1][w][0][l] = a0a + a0b;
      part[s & 1][w][1][l] = a1a + a1b;
      __syncthreads();

      if (w < 2) {
        f32x4 r = accx;
#pragma unroll
        for (int ww = 0; ww < 8; ++ww) r += part[s & 1][ww][w][l];

        unsigned int* dstg = hy_ex + (size_t)(wb * 8 + g) * 16384;
#pragma unroll
        for (int i = 0; i < 4; ++i) {
          float a = r[i] + bias_c;
          float th = fast_tanhf(a);
          hz[i] += DT * (th - gam * hy[i] - ep * hz[i]);
          hy[i] += DT * hz[i];
          const int rr = kg * 4 + i;
          unsigned short hb = f2bf(hy[i]);
          unsigned short lb = f2bf(hy[i] - bf2f(hb));
          unsigned int oh = (unsigned int)__shfl_xor((int)hb, 1, 64);
          unsigned int ol = (unsigned int)__shfl_xor((int)lb, 1, 64);
          if (!(lc & 1)) {  // even col stores the (c, c+1) pair
            const int u32idx = (ktc * 512 + rr * 32 + kgc * 8 + sh) >> 1;
            stpub<F>(dstg + u32idx, (unsigned int)hb | (oh << 16));
            stpub<F>(dstg + 8192 + u32idx, (unsigned int)lb | (ol << 16));
          }
        }
        drain_vm();  // wave-local: MY publish stores committed (L2 fast / IC slow)
        if (l == 0) stflag<F>(myflag, (unsigned int)(s + 1));

        // ---- off the critical path: out[] stores, then x(s+1) prefetch ----
#pragma unroll
        for (int i = 0; i < 4; ++i)
          out[((size_t)(g * 16 + kg * 4 + i) * LSEQ + s) * NH + myc] = hy[i];
        const float* xs2 = xlane + (size_t)(s + 1 < LSEQ ? s + 1 : s) * NI;
#pragma unroll
        for (int kt = 0; kt < 3; ++kt) {
          xr[2 * kt] = *(const f32x4*)(xs2 + kt * 32);
          xr[2 * kt + 1] = *(const f32x4*)(xs2 + kt * 32 + 4);
        }
      }
    }
  };

  if (fastm)
    run(BoolC<true>{});
  else
    run(BoolC<false>{});
}

extern "C" void kernel_launch(void* const* d_in, const int* in_sizes, int n_in,
                              void* d_out, int out_size, void* d_ws, size_t ws_size,
                              hipStream_t stream) {
  const float* x = (const float*)d_in[0];
  const float* x2h = (const float*)d_in[1];
  const float* h2h = (const float*)d_in[2];
  const float* bias = (const float*)d_in[3];
  const float* gam = (const float*)d_in[4];
  const float* eps = (const float*)d_in[5];
  float* out = (float*)d_out;

  unsigned int* flags = (unsigned int*)d_ws;                   // 32KB per-wave flags + tables
  unsigned int* hy_ex = (unsigned int*)((char*)d_ws + 65536);  // 3 bufs x 8 groups x 64KB

  // zero flags + discovery + mapping table every call (step 0 never reads hy_ex)
  hipMemsetAsync(d_ws, 0, 65536, stream);

  ron_kernel<<<dim3(256), dim3(512), 0, stream>>>(x, x2h, h2h, bias, gam, eps, out, flags, hy_ex);
}

// Round 10
// 2113.586 us; speedup vs baseline: 4.9358x; 4.9358x over previous
//
#include <hip/hip_runtime.h>
#include <math.h>

typedef short short8 __attribute__((ext_vector_type(8)));
typedef float f32x4 __attribute__((ext_vector_type(4)));
typedef unsigned long long u64;
typedef u64 u64x2 __attribute__((ext_vector_type(2)));

#define DT 0.042f
#define LSEQ 512
#define NI 96
#define NH 1024

static __device__ __forceinline__ unsigned short f2bf(float f) {
  unsigned int u = __builtin_bit_cast(unsigned int, f);
  return (unsigned short)((u + 0x7fffu + ((u >> 16) & 1u)) >> 16);
}
static __device__ __forceinline__ float bf2f(unsigned short h) {
  unsigned int u = ((unsigned int)h) << 16;
  return __builtin_bit_cast(float, u);
}
static __device__ __forceinline__ float fast_tanhf(float a) {
  float ax = __builtin_fabsf(a);
  float e = __expf(2.0f * ax);  // overflow -> inf -> t = 1, no NaN
  float t = 1.0f - 2.0f / (e + 1.0f);
  return a < 0.0f ? -t : t;
}

// DATA ops scope-templated: F=true -> sc0 (XCD-local L2, verified co-XCD groups).
// FLAGS always relaxed AGENT atomics (IC): bypass L1 reliably — r9 proved sc0
// polling is L1-sticky (20us/step); agent flags are proven (r2/3/5/8).
template <bool F>
static __device__ __forceinline__ void ld16_issue(u64x2* dst, const u64* p) {
  if constexpr (F) {
    asm volatile("global_load_dwordx4 %0, %1, off sc0" : "=v"(*dst) : "v"(p) : "memory");
  } else {
    u64 a = __hip_atomic_load(p, __ATOMIC_RELAXED, __HIP_MEMORY_SCOPE_AGENT);
    u64 b = __hip_atomic_load(p + 1, __ATOMIC_RELAXED, __HIP_MEMORY_SCOPE_AGENT);
    *dst = (u64x2){a, b};
  }
}
template <bool F>
static __device__ __forceinline__ void ld_fence() {  // A-frags resident (rule #18)
  if constexpr (F) {
    asm volatile("s_waitcnt vmcnt(0)" ::: "memory");
    __builtin_amdgcn_sched_barrier(0);
  }
}
template <bool F>
static __device__ __forceinline__ void stpub(unsigned int* p, unsigned int v) {
  if constexpr (F)
    asm volatile("global_store_dword %0, %1, off sc0" ::"v"(p), "v"(v) : "memory");
  else
    __hip_atomic_store(p, v, __ATOMIC_RELAXED, __HIP_MEMORY_SCOPE_AGENT);
}
static __device__ __forceinline__ void drain_vm() {  // wave-local: my stores committed
  asm volatile("s_waitcnt vmcnt(0)" ::: "memory");
  __builtin_amdgcn_sched_barrier(0);
}
template <bool B> struct BoolC { static constexpr bool value = B; };

// 256 blocks x 512 threads. Group g (16 batch rows) x col-block jb (32 cols); 8 waves
// k-split 1024 (wave w: k-tiles w*4..+3). PER-WAVE AGENT flags (2/block): each
// publishing wave drains its own sc0 stores then posts its own flag — no block-wide
// drain, ONE barrier/step (part[] double-buffered by s&1); waves 2-7 run ahead into
// step s+1 while waves 0/1 finish step s. Triple-buffered hy_ex: publishes happen
// post-barrier, and the 8 waves' watch sets union to all 32 producers, so buffer
// (s-3)%3 is fully read before overwrite (r5 invariant, re-derived for this shape).
// Mapping (g, jb, fast) from block-0-built table of ACTUAL XCD placement (r8-proven);
// fast groups put hy_ex DATA in their XCD's L2 via sc0; leftovers use agent/IC.
__global__ __launch_bounds__(512, 2) void ron_kernel(
    const float* __restrict__ x, const float* __restrict__ x2h,
    const float* __restrict__ h2h, const float* __restrict__ bias,
    const float* __restrict__ gam_, const float* __restrict__ eps_,
    float* __restrict__ out, unsigned int* __restrict__ flags,
    unsigned int* __restrict__ hy_ex) {
  const int tid = threadIdx.x;
  const int w = tid >> 6;  // 0..7
  const int l = tid & 63;
  const int lc = l & 15;
  const int kg = l >> 4;

  __shared__ f32x4 part[2][8][2][64];  // 32KB, double-buffered by s&1
  __shared__ int info_sh;

  unsigned int* base = flags + 8192;  // byte 32768
  unsigned int* xcdtab = base;        // [0..255]
  unsigned int* ctr = base + 256;
  unsigned int* abortw = base + 257;
  unsigned int* enttab = base + 272;  // [0..255]

  // ---- publish my XCD (every block) ----
  if (tid == 0) {
    unsigned int myxcd = __builtin_amdgcn_s_getreg(63508) & 15u;  // hwreg(XCC_ID=20,0,32)
    __hip_atomic_store(xcdtab + blockIdx.x, 0x100u | myxcd, __ATOMIC_RELAXED,
                       __HIP_MEMORY_SCOPE_AGENT);
    __hip_atomic_fetch_add(ctr, 1u, __ATOMIC_RELAXED, __HIP_MEMORY_SCOPE_AGENT);
  }

  // ---- block 0: build the (g, jb, mode) table — single source of truth (r8-proven) ----
  if (blockIdx.x == 0 && tid == 0) {
    int gu = 0;
    while (__hip_atomic_load(ctr, __ATOMIC_RELAXED, __HIP_MEMORY_SCOPE_AGENT) < 256u) {
      if (++gu > (1 << 17)) break;
      __builtin_amdgcn_s_sleep(8);
    }
    bool ok = (gu <= (1 << 17));
    unsigned char xs[256];
    if (ok) {
      for (int i = 0; i < 256; ++i) {
        unsigned int v = __hip_atomic_load(xcdtab + i, __ATOMIC_RELAXED, __HIP_MEMORY_SCOPE_AGENT);
        int g2 = 0;
        while (v == 0 && ++g2 <= 8192) {
          __builtin_amdgcn_s_sleep(2);
          v = __hip_atomic_load(xcdtab + i, __ATOMIC_RELAXED, __HIP_MEMORY_SCOPE_AGENT);
        }
        if (v == 0) { ok = false; break; }
        xs[i] = (unsigned char)(v & 15u);
      }
    }
    unsigned int ent[256];
    if (ok) {
      int gidx = 0, nl = 0;
      unsigned char left[256], tmp[256];
      for (unsigned int xc = 0; xc < 16u && gidx < 8; ++xc) {
        int cnt = 0;
        for (int i = 0; i < 256; ++i)
          if (xs[i] == (unsigned char)xc) tmp[cnt++] = (unsigned char)i;
        int p = 0;
        while (cnt - p >= 32 && gidx < 8) {  // exact-32 co-XCD set -> fast
          for (int k2 = 0; k2 < 32; ++k2)
            ent[tmp[p + k2]] = 1u | ((unsigned)gidx << 1) | ((unsigned)k2 << 4) | (1u << 9);
          ++gidx; p += 32;
        }
        for (; p < cnt; ++p) left[nl++] = tmp[p];
      }
      int li = 0;
      while (gidx < 8) {  // mixed leftovers -> slow (agent/IC, proven)
        for (int k2 = 0; k2 < 32 && li < nl; ++k2, ++li)
          ent[left[li]] = 1u | ((unsigned)gidx << 1) | ((unsigned)k2 << 4);
        ++gidx;
      }
    } else {
      for (int i = 0; i < 256; ++i)
        ent[i] = 1u | ((unsigned)(i & 7) << 1) | ((unsigned)(i >> 3) << 4);
    }
    for (int i = 0; i < 256; ++i)
      __hip_atomic_store(enttab + i, ent[i], __ATOMIC_RELAXED, __HIP_MEMORY_SCOPE_AGENT);
  }

  // ---- every block: fetch my entry ----
  if (tid == 0) {
    unsigned int e = 0;
    int gu = 0;
    for (;;) {
      e = __hip_atomic_load(enttab + blockIdx.x, __ATOMIC_RELAXED, __HIP_MEMORY_SCOPE_AGENT);
      if (e || ++gu > (1 << 17)) break;
      __builtin_amdgcn_s_sleep(16);
    }
    if (!e) e = 1u | ((unsigned)(blockIdx.x & 7) << 1) | ((unsigned)(blockIdx.x >> 3) << 4);
    info_sh = (int)e;
  }
  __syncthreads();
  const unsigned int ent = (unsigned int)info_sh;
  const int g = (ent >> 1) & 7;
  const int jb = (ent >> 4) & 31;
  const bool fastm = ((ent >> 9) & 1) != 0;

  // ---- one-time: h2h k-slice (wave's 4 k-tiles) x 2 col-tiles, hi/lo bf16 ----
  short8 wfh[4][2], wfl[4][2];
#pragma unroll
  for (int j = 0; j < 4; ++j) {
    const int krow = (w * 4 + j) * 32 + kg * 8;
#pragma unroll
    for (int t = 0; t < 2; ++t) {
      const int c = jb * 32 + t * 16 + lc;
#pragma unroll
      for (int jj = 0; jj < 8; ++jj) {
        float v = h2h[(size_t)(krow + jj) * NH + c];
        unsigned short hb = f2bf(v);
        wfh[j][t][jj] = (short)hb;
        wfl[j][t][jj] = (short)f2bf(v - bf2f(hb));
      }
    }
  }
  const int myc = jb * 32 + w * 16 + lc;  // owned col (waves 0,1 only)
  short8 xwh[3], xwl[3];
  float bias_c = 0.f, gam = 0.f, ep = 0.f;
  if (w < 2) {
#pragma unroll
    for (int kt = 0; kt < 3; ++kt)
#pragma unroll
      for (int jj = 0; jj < 8; ++jj) {
        float v = x2h[(size_t)(kt * 32 + kg * 8 + jj) * NH + myc];
        unsigned short hb = f2bf(v);
        xwh[kt][jj] = (short)hb;
        xwl[kt][jj] = (short)f2bf(v - bf2f(hb));
      }
    bias_c = bias[myc];
    gam = gam_[myc];
    ep = eps_[myc];
  }

  float hy[4] = {0.f, 0.f, 0.f, 0.f};
  float hz[4] = {0.f, 0.f, 0.f, 0.f};
  const float* xlane = x + (size_t)(g * 16 + lc) * LSEQ * NI + kg * 8;
  const int aoff = lc * 8 + kg * 2;  // u64 units within a 128-u64 chunk
  // per-wave flags: 64 per group, 64B-spaced. myflag used by waves 0,1 only.
  unsigned int* myflag = flags + (size_t)(g * 64 + jb * 2 + w) * 16;
  unsigned int* watch =
      flags + (size_t)(g * 64 + (w * 4 + ((l >> 1) & 3)) * 2 + (l & 1)) * 16;
  const int ktc = myc >> 5, kgc = (myc >> 3) & 3, sh = myc & 7;

  // ---- prefetch x for s=0 ----
  f32x4 xr[6];
  if (w < 2) {
#pragma unroll
    for (int kt = 0; kt < 3; ++kt) {
      xr[2 * kt] = *(const f32x4*)(xlane + kt * 32);
      xr[2 * kt + 1] = *(const f32x4*)(xlane + kt * 32 + 4);
    }
  }

  auto run = [&](auto fc) {
    constexpr bool F = decltype(fc)::value;
    bool noSync = false;  // watchdog: trip -> never wait again (fast, visible failure)
    for (int s = 0; s < LSEQ; ++s) {
      const int wb = s % 3;            // write buffer
      const int rb = wb ? wb - 1 : 2;  // read buffer = (s-1)%3

      // ---- pack x(s) frags from prefetched regs ----
      short8 axh[3], axl[3];
      if (w < 2) {
#pragma unroll
        for (int kt = 0; kt < 3; ++kt) {
#pragma unroll
          for (int jj = 0; jj < 4; ++jj) {
            unsigned short hb = f2bf(xr[2 * kt][jj]);
            axh[kt][jj] = (short)hb;
            axl[kt][jj] = (short)f2bf(xr[2 * kt][jj] - bf2f(hb));
            unsigned short hb2 = f2bf(xr[2 * kt + 1][jj]);
            axh[kt][jj + 4] = (short)hb2;
            axl[kt][jj + 4] = (short)f2bf(xr[2 * kt + 1][jj] - bf2f(hb2));
          }
        }
      }

      f32x4 a0a = {0.f, 0.f, 0.f, 0.f}, a0b = {0.f, 0.f, 0.f, 0.f};
      f32x4 a1a = {0.f, 0.f, 0.f, 0.f}, a1b = {0.f, 0.f, 0.f, 0.f};
      f32x4 accx = {0.f, 0.f, 0.f, 0.f};
      u64x2 hq[4], lq[4];

      if (s) {
        // ---- wait: 4 suppliers x 2 publishing waves = 8 AGENT flags (lanes l&7) ----
        if (!noSync) {
          int guard = 0;
          for (;;) {
            unsigned int v = __hip_atomic_load(watch, __ATOMIC_RELAXED, __HIP_MEMORY_SCOPE_AGENT);
            if (!__any((int)v < s)) break;
            if ((++guard & 255) == 0) {
              if (__hip_atomic_load(abortw, __ATOMIC_RELAXED, __HIP_MEMORY_SCOPE_AGENT) != 0u ||
                  guard > (1 << 16)) {
                __hip_atomic_store(abortw, 1u, __ATOMIC_RELAXED, __HIP_MEMORY_SCOPE_AGENT);
                noSync = true;
                break;
              }
            }
            __builtin_amdgcn_s_sleep(1);
          }
        }
        asm volatile("" ::: "memory");  // keep A-loads below the spin

        // ---- issue A-fragment loads (wave's k-quarter: 8 x 16B, sc0 on fast path) ----
        const u64* srcg = (const u64*)hy_ex + (size_t)(rb * 8 + g) * 8192;
#pragma unroll
        for (int j = 0; j < 4; ++j) {
          const int idx = (w * 4 + j) * 128 + aoff;
          ld16_issue<F>(&hq[j], srcg + idx);
          ld16_issue<F>(&lq[j], srcg + 4096 + idx);
        }
      }

      // ---- x-projection MFMAs (waves 0,1): overlap the A-load round trip ----
      if (w < 2) {
#pragma unroll
        for (int kt = 0; kt < 3; ++kt) {
          accx = __builtin_amdgcn_mfma_f32_16x16x32_bf16(axh[kt], xwh[kt], accx, 0, 0, 0);
          accx = __builtin_amdgcn_mfma_f32_16x16x32_bf16(axl[kt], xwh[kt], accx, 0, 0, 0);
          accx = __builtin_amdgcn_mfma_f32_16x16x32_bf16(axh[kt], xwl[kt], accx, 0, 0, 0);
        }
      }

      if (s) {
        ld_fence<F>();
#pragma unroll
        for (int j = 0; j < 4; ++j) {
          short8 fh = __builtin_bit_cast(short8, hq[j]);
          short8 fl = __builtin_bit_cast(short8, lq[j]);
          if (j & 1) {
            a0b = __builtin_amdgcn_mfma_f32_16x16x32_bf16(fh, wfh[j][0], a0b, 0, 0, 0);
            a1b = __builtin_amdgcn_mfma_f32_16x16x32_bf16(fh, wfh[j][1], a1b, 0, 0, 0);
            a0b = __builtin_amdgcn_mfma_f32_16x16x32_bf16(fl, wfh[j][0], a0b, 0, 0, 0);
            a1b = __builtin_amdgcn_mfma_f32_16x16x32_bf16(fl, wfh[j][1], a1b, 0, 0, 0);
            a0b = __builtin_amdgcn_mfma_f32_16x16x32_bf16(fh, wfl[j][0], a0b, 0, 0, 0);
            a1b = __builtin_amdgcn_mfma_f32_16x16x32_bf16(fh, wfl[j][1], a1b, 0, 0, 0);
          } else {
            a0a = __builtin_amdgcn_mfma_f32_16x16x32_bf16(fh, wfh[j][0], a0a, 0, 0, 0);
            a1a = __builtin_amdgcn_mfma_f32_16x16x32_bf16(fh, wfh[j][1], a1a, 0, 0, 0);
            a0a = __builtin_amdgcn_mfma_f32_16x16x32_bf16(fl, wfh[j][0], a0a, 0, 0, 0);
            a1a = __builtin_amdgcn_mfma_f32_16x16x32_bf16(fl, wfh[j][1], a1a, 0, 0, 0);
            a0a = __builtin_amdgcn_mfma_f32_16x16x32_bf16(fh, wfl[j][0], a0a, 0, 0, 0);
            a1a = __builtin_amdgcn_mfma_f32_16x16x32_bf16(fh, wfl[j][1], a1a, 0, 0, 0);
          }
        }
      }

      // ---- cross-wave k-reduction via LDS (double-buffered; ONE barrier/step) ----
      part[s & 1][w][0][l] = a0a + a0b;
      part[s & 1][w][1][l] = a1a + a1b;
      __syncthreads();
      // waves 2-7: nothing more this step -> run ahead into step s+1 (spin/A-loads)

      if (w < 2) {
        f32x4 r = accx;
#pragma unroll
        for (int ww = 0; ww < 8; ++ww) r += part[s & 1][ww][w][l];

        unsigned int* dstg = hy_ex + (size_t)(wb * 8 + g) * 16384;
#pragma unroll
        for (int i = 0; i < 4; ++i) {
          float a = r[i] + bias_c;
          float th = fast_tanhf(a);
          hz[i] += DT * (th - gam * hy[i] - ep * hz[i]);
          hy[i] += DT * hz[i];
          const int rr = kg * 4 + i;
          unsigned short hb = f2bf(hy[i]);
          unsigned short lb = f2bf(hy[i] - bf2f(hb));
          unsigned int oh = (unsigned int)__shfl_xor((int)hb, 1, 64);
          unsigned int ol = (unsigned int)__shfl_xor((int)lb, 1, 64);
          if (!(lc & 1)) {  // even col stores the (c, c+1) pair
            const int u32idx = (ktc * 512 + rr * 32 + kgc * 8 + sh) >> 1;
            stpub<F>(dstg + u32idx, (unsigned int)hb | (oh << 16));
            stpub<F>(dstg + 8192 + u32idx, (unsigned int)lb | (ol << 16));
          }
        }
        drain_vm();  // wave-local: MY publish stores committed (L2 fast / IC slow)
        if (l == 0)
          __hip_atomic_store(myflag, (unsigned int)(s + 1), __ATOMIC_RELAXED,
                             __HIP_MEMORY_SCOPE_AGENT);

        // ---- off the critical path: out[] stores, then x(s+1) prefetch ----
#pragma unroll
        for (int i = 0; i < 4; ++i)
          out[((size_t)(g * 16 + kg * 4 + i) * LSEQ + s) * NH + myc] = hy[i];
        const float* xs2 = xlane + (size_t)(s + 1 < LSEQ ? s + 1 : s) * NI;
#pragma unroll
        for (int kt = 0; kt < 3; ++kt) {
          xr[2 * kt] = *(const f32x4*)(xs2 + kt * 32);
          xr[2 * kt + 1] = *(const f32x4*)(xs2 + kt * 32 + 4);
        }
      }
    }
  };

  if (fastm)
    run(BoolC<true>{});
  else
    run(BoolC<false>{});
}

extern "C" void kernel_launch(void* const* d_in, const int* in_sizes, int n_in,
                              void* d_out, int out_size, void* d_ws, size_t ws_size,
                              hipStream_t stream) {
  const float* x = (const float*)d_in[0];
  const float* x2h = (const float*)d_in[1];
  const float* h2h = (const float*)d_in[2];
  const float* bias = (const float*)d_in[3];
  const float* gam = (const float*)d_in[4];
  const float* eps = (const float*)d_in[5];
  float* out = (float*)d_out;

  unsigned int* flags = (unsigned int*)d_ws;                   // 32KB per-wave flags + tables
  unsigned int* hy_ex = (unsigned int*)((char*)d_ws + 65536);  // 3 bufs x 8 groups x 64KB

  // zero flags + discovery + mapping table every call (step 0 never reads hy_ex)
  hipMemsetAsync(d_ws, 0, 65536, stream);

  ron_kernel<<<dim3(256), dim3(512), 0, stream>>>(x, x2h, h2h, bias, gam, eps, out, flags, hy_ex);
}